// Round 2
// baseline (271.260 us; speedup 1.0000x reference)
//
#include <hip/hip_runtime.h>

#define DEV __device__ __forceinline__

DEV float fexp2(float x) { return __builtin_amdgcn_exp2f(x); }
DEV float frcp(float x) { return __builtin_amdgcn_rcpf(x); }

// Broadcast lane (quad_base + S) to all 4 lanes of the quad via DPP quad_perm.
template <int S>
DEV float qbcast(float x) {
  int i = __float_as_int(x);
  i = __builtin_amdgcn_update_dpp(0, i, S * 0x55, 0xF, 0xF, true);
  return __int_as_float(i);
}

// Full-wave lane gather: dst lane gets src value from lane (byte_addr>>2).
DEV float bperm(int byte_addr, float x) {
  return __int_as_float(
      __builtin_amdgcn_ds_bpermute(byte_addr, __float_as_int(x)));
}

struct Cell {
  float wih[5][5];
  float whh[5][5];
  float b[5];
};

DEV void load_cell(Cell& W, const float* __restrict__ Wih,
                   const float* __restrict__ Whh, const float* __restrict__ bih,
                   const float* __restrict__ bhh, int s) {
#pragma unroll
  for (int j = 0; j < 5; ++j) {
    int r = 5 * s + j;
#pragma unroll
    for (int k = 0; k < 5; ++k) {
      W.wih[j][k] = Wih[r * 5 + k];
      W.whh[j][k] = Whh[r * 5 + k];
    }
    W.b[j] = bih[r] + bhh[r];
  }
}

// One LSTM cell step. Lane s of each quad computes gate group s (i,f,g,o).
// act(x) = m2 * rcp(1 + exp2(kexp*x)) + a2 unifies sigmoid (s!=2) / tanh (s==2)
DEV void cell_step(const Cell& W, float kexp, float m2, float a2,
                   const float x[5], float h[5], float c[5]) {
  float a[5];
#pragma unroll
  for (int j = 0; j < 5; ++j) {
    float acc = W.b[j];
#pragma unroll
    for (int k = 0; k < 5; ++k) acc = fmaf(W.wih[j][k], x[k], acc);
#pragma unroll
    for (int k = 0; k < 5; ++k) acc = fmaf(W.whh[j][k], h[k], acc);
    float e = fexp2(acc * kexp);
    float r = frcp(1.0f + e);
    a[j] = fmaf(m2, r, a2);
  }
#pragma unroll
  for (int j = 0; j < 5; ++j) {
    float I = qbcast<0>(a[j]);
    float F = qbcast<1>(a[j]);
    float G = qbcast<2>(a[j]);
    float O = qbcast<3>(a[j]);
    float cj = fmaf(F, c[j], I * G);
    c[j] = cj;
    float e2 = fexp2(cj * -2.885390082f);  // tanh(c)
    float tc = fmaf(2.0f, frcp(1.0f + e2), -1.0f);
    h[j] = O * tc;
  }
}

// One wave per block. Lanes: quad q = lane>>2 (0..15), q==15 idle for RNN.
// q -> (element e_w = q/3 in 0..4, cell = q%3). Cell 2 (lstm2b) runs one
// timestep behind cell 1 (lstm2a), receiving h2a via ds_bpermute from lane-4.
__global__ __launch_bounds__(64, 4) void rnn_pipe_kernel(
    const float* __restrict__ x1, const float* __restrict__ x2,
    const float* __restrict__ Wih1, const float* __restrict__ Whh1,
    const float* __restrict__ bih1, const float* __restrict__ bhh1,
    const float* __restrict__ Wih2a, const float* __restrict__ Whh2a,
    const float* __restrict__ bih2a, const float* __restrict__ bhh2a,
    const float* __restrict__ Wih2b, const float* __restrict__ Whh2b,
    const float* __restrict__ bih2b, const float* __restrict__ bhh2b,
    const float* __restrict__ W1, const float* __restrict__ b1,
    const float* __restrict__ W2, const float* __restrict__ b2,
    const float* __restrict__ W3, const float* __restrict__ b3,
    const float* __restrict__ W4, const float* __restrict__ b4,
    const float* __restrict__ W5, const float* __restrict__ b5,
    float* __restrict__ out, int B) {
  __shared__ float sIn[5][20];
  __shared__ float sA[5][32];
  __shared__ float sB[5][32];

  const int lane = threadIdx.x;  // 0..63
  const int q = lane >> 2;
  const int s = lane & 3;

  if (q < 15) {
    const int e_w = q / 3;
    const int cell = q - e_w * 3;
    const int eg = blockIdx.x * 5 + e_w;
    const int egc = (eg < B) ? eg : (B - 1);
    const bool c2 = (cell == 2);
    const float* xbase = (cell == 1) ? x2 : x1;
    const float* px = xbase + (size_t)egc * 640;

    Cell W;
    if (cell == 0)
      load_cell(W, Wih1, Whh1, bih1, bhh1, s);
    else if (cell == 1)
      load_cell(W, Wih2a, Whh2a, bih2a, bhh2a, s);
    else
      load_cell(W, Wih2b, Whh2b, bih2b, bhh2b, s);

    const float kexp = (s == 2) ? -2.885390082f : -1.442695041f;
    const float m2 = (s == 2) ? 2.0f : 1.0f;
    const float a2 = (s == 2) ? -1.0f : 0.0f;
    // cell-2 lanes gather from their element's cell-1 quad (lane-4)
    const int bpaddr = ((c2 ? lane - 4 : lane) << 2);

    float h[5], c[5], hp[5], xcur[5];
#pragma unroll
    for (int k = 0; k < 5; ++k) {
      h[k] = c[k] = hp[k] = 0.0f;
      xcur[k] = px[k];
    }

    for (int t = 0; t < 128; ++t) {
      const int tn = (t < 127) ? t + 1 : 127;
      float xn[5];
#pragma unroll
      for (int k = 0; k < 5; ++k) xn[k] = px[tn * 5 + k];  // prefetch
      float xin[5];
#pragma unroll
      for (int k = 0; k < 5; ++k) xin[k] = c2 ? hp[k] : xcur[k];
      cell_step(W, kexp, m2, a2, xin, h, c);
      if (t == 0 && c2) {
        // cell-2's iter-0 step consumed garbage (h2a(-1)); reset its state so
        // its real step 0 (executed at iter 1 with h2a(0)) starts from zeros.
#pragma unroll
        for (int k = 0; k < 5; ++k) {
          h[k] = 0.0f;
          c[k] = 0.0f;
        }
      }
      // hand cell-1's h2a(t) to cell-2 lanes (consumed next iteration)
#pragma unroll
      for (int k = 0; k < 5; ++k) hp[k] = bperm(bpaddr, h[k]);
#pragma unroll
      for (int k = 0; k < 5; ++k) xcur[k] = xn[k];
    }
    // cell-2 trails by one step: consume h2a(127)
    if (c2) {
      float xin[5];
#pragma unroll
      for (int k = 0; k < 5; ++k) xin[k] = hp[k];
      cell_step(W, kexp, m2, a2, xin, h, c);
    }

    // Stage FC inputs: in0 = [x1_last, x2_last, h1, h2b]
    if (eg < B && s == 0) {
      if (cell == 0) {
#pragma unroll
        for (int k = 0; k < 5; ++k) {
          sIn[e_w][k] = xcur[k];       // x1[:, -1, :]
          sIn[e_w][10 + k] = h[k];     // out1
        }
      } else if (cell == 1) {
#pragma unroll
        for (int k = 0; k < 5; ++k) sIn[e_w][5 + k] = xcur[k];  // x2[:, -1, :]
      } else {
#pragma unroll
        for (int k = 0; k < 5; ++k) sIn[e_w][15 + k] = h[k];  // out2
      }
    }
  }
  __syncthreads();

  // FC stack, task-split across the wave; weights from global (L1 broadcast).
  for (int task = lane; task < 160; task += 64) {
    int e = task >> 5, n = task & 31;
    float acc = b1[n];
#pragma unroll
    for (int k = 0; k < 20; ++k) acc = fmaf(W1[n * 20 + k], sIn[e][k], acc);
    sA[e][n] = fmaxf(acc, 0.0f);
  }
  __syncthreads();
  for (int task = lane; task < 160; task += 64) {
    int e = task >> 5, n = task & 31;
    float acc = b2[n];
#pragma unroll
    for (int k = 0; k < 32; ++k) acc = fmaf(W2[n * 32 + k], sA[e][k], acc);
    sB[e][n] = fmaxf(acc, 0.0f);
  }
  __syncthreads();
  for (int task = lane; task < 80; task += 64) {
    int e = task >> 4, n = task & 15;
    float acc = b3[n];
#pragma unroll
    for (int k = 0; k < 32; ++k) acc = fmaf(W3[n * 32 + k], sB[e][k], acc);
    sA[e][n] = fmaxf(acc, 0.0f);  // reuse sA cols 0..15
  }
  __syncthreads();
  for (int task = lane; task < 80; task += 64) {
    int e = task >> 4, n = task & 15;
    float acc = b4[n];
#pragma unroll
    for (int k = 0; k < 16; ++k) acc = fmaf(W4[n * 16 + k], sA[e][k], acc);
    sB[e][n] = fmaxf(acc, 0.0f);
  }
  __syncthreads();
  for (int task = lane; task < 25; task += 64) {
    int e = task / 5, n = task - 5 * (task / 5);
    float acc = b5[n];
#pragma unroll
    for (int k = 0; k < 16; ++k) acc = fmaf(W5[n * 16 + k], sB[e][k], acc);
    int eg = blockIdx.x * 5 + e;
    if (eg < B) out[(size_t)eg * 5 + n] = acc;
  }
}

extern "C" void kernel_launch(void* const* d_in, const int* in_sizes, int n_in,
                              void* d_out, int out_size, void* d_ws,
                              size_t ws_size, hipStream_t stream) {
  const float* x1 = (const float*)d_in[0];
  const float* x2 = (const float*)d_in[1];
  const float* Wih1 = (const float*)d_in[2];
  const float* Whh1 = (const float*)d_in[3];
  const float* bih1 = (const float*)d_in[4];
  const float* bhh1 = (const float*)d_in[5];
  const float* Wih2a = (const float*)d_in[6];
  const float* Whh2a = (const float*)d_in[7];
  const float* bih2a = (const float*)d_in[8];
  const float* bhh2a = (const float*)d_in[9];
  const float* Wih2b = (const float*)d_in[10];
  const float* Whh2b = (const float*)d_in[11];
  const float* bih2b = (const float*)d_in[12];
  const float* bhh2b = (const float*)d_in[13];
  const float* W1 = (const float*)d_in[14];
  const float* b1 = (const float*)d_in[15];
  const float* W2 = (const float*)d_in[16];
  const float* b2 = (const float*)d_in[17];
  const float* W3 = (const float*)d_in[18];
  const float* b3 = (const float*)d_in[19];
  const float* W4 = (const float*)d_in[20];
  const float* b4 = (const float*)d_in[21];
  const float* W5 = (const float*)d_in[22];
  const float* b5 = (const float*)d_in[23];

  int B = in_sizes[0] / 640;  // [B, 128, 5]
  int blocks = (B + 4) / 5;   // 5 elements per 64-thread block

  rnn_pipe_kernel<<<blocks, 64, 0, stream>>>(
      x1, x2, Wih1, Whh1, bih1, bhh1, Wih2a, Whh2a, bih2a, bhh2a, Wih2b, Whh2b,
      bih2b, bhh2b, W1, b1, W2, b2, W3, b3, W4, b4, W5, b5, (float*)d_out, B);
}